// Round 13
// baseline (374.942 us; speedup 1.0000x reference)
//
#include <hip/hip_runtime.h>
#include <cstdint>
#include <cstddef>

typedef _Float16 f16;
typedef __attribute__((ext_vector_type(8))) _Float16 f16x8;
typedef __attribute__((ext_vector_type(4))) _Float16 f16x4;
typedef __attribute__((ext_vector_type(4))) float f32x4;

constexpr int kB  = 2;
constexpr int kS  = 2048;
constexpr int kD  = 2048;
constexpr int kH  = 16;
constexpr int kL  = 64;
constexpr int kHL = kH * kL;   // 1024
constexpr int kBS = kB * kS;   // 4096

__device__ __forceinline__ void load_lds16(const void* g, void* l) {
  __builtin_amdgcn_global_load_lds((const __attribute__((address_space(1))) void*)g,
                                   (__attribute__((address_space(3))) void*)l, 16, 0, 0);
}

__device__ __forceinline__ f32x4 mfma16(f16x8 a, f16x8 b, f32x4 c) {
  return __builtin_amdgcn_mfma_f32_16x16x32_f16(a, b, c, 0, 0, 0);
}

// ---------- merged fp32 -> fp16 cast: z=0..2 q/k/v (8M elems), z=3 Wq (4M elems) ----------
__global__ void cast4(const float* __restrict__ a, const float* __restrict__ b,
                      const float* __restrict__ c, const float* __restrict__ d,
                      f16* __restrict__ oa, f16* __restrict__ ob,
                      f16* __restrict__ oc, f16* __restrict__ od) {
  const int z = blockIdx.z;
  int i = blockIdx.x * 256 + threadIdx.x;
  if (z == 3 && i >= kD * kD / 4) return;
  const float* in = z == 0 ? a : z == 1 ? b : z == 2 ? c : d;
  f16* out = z == 0 ? oa : z == 1 ? ob : z == 2 ? oc : od;
  float4 f = ((const float4*)in)[i];
  f16x4 o; o[0] = (f16)f.x; o[1] = (f16)f.y; o[2] = (f16)f.z; o[3] = (f16)f.w;
  ((f16x4*)out)[i] = o;
}

// ---------- LDS-tiled transpose-cast: in[R][C] fp32 -> out[C][R] fp16 ----------
__device__ __forceinline__ void transpose_body(const float* __restrict__ in,
                                               f16* __restrict__ out, int R, int C) {
  const int r0 = blockIdx.y * 64, c0 = blockIdx.x * 64;
  __shared__ float tile[64][65];
  const int t = threadIdx.x;
  const int cc = t & 63, rr = t >> 6;
#pragma unroll
  for (int p = 0; p < 16; p++) {
    int r = p * 4 + rr;
    tile[r][cc] = in[(size_t)(r0 + r) * C + c0 + cc];
  }
  __syncthreads();
#pragma unroll
  for (int p = 0; p < 16; p++) {
    int c = p * 4 + rr;
    out[(size_t)(c0 + c) * R + r0 + cc] = (f16)tile[cc][c];
  }
}

// z=0: Wlk [2048][1024]->[1024][2048] ; z=1: Wlv same ; z=2: Wout [2048][2048] transposed
__global__ __launch_bounds__(256) void transpose3(const float* __restrict__ Wlk,
                                                  const float* __restrict__ Wlv,
                                                  const float* __restrict__ Wout,
                                                  f16* __restrict__ Wlkt,
                                                  f16* __restrict__ Wlvt,
                                                  f16* __restrict__ WoutT) {
  const int z = blockIdx.z;
  if (z < 2 && blockIdx.x >= 16) return;
  if (z == 0) transpose_body(Wlk, Wlkt, 2048, 1024);
  else if (z == 1) transpose_body(Wlv, Wlvt, 2048, 1024);
  else transpose_body(Wout, WoutT, 2048, 2048);
}

__global__ void fold_bq(const float* __restrict__ bq, const float* __restrict__ Wkr,
                        float* __restrict__ bql) {
  int hl = blockIdx.x * 256 + threadIdx.x;
  if (hl >= kHL) return;
  int h = hl >> 6, l = hl & 63;
  float s = 0.f;
  for (int c = 0; c < 128; c++) s += bq[h * 128 + c] * Wkr[l * 128 + c];
  bql[hl] = s;
}

// ---------- direct per-head fold GEMMs ----------
// z=0: Wqlt[h*64+l][d]  = sum_c Wkr[l][c] * Wq16 [d][h*128+c]   (tile 64 x 128)
// z=1: W2t [d][h*64+l]  = sum_c Wvr[l][c] * WoutT[d][h*128+c]   (tile 128 x 64)
__global__ __launch_bounds__(256) void fold2(const float* __restrict__ Wkr,
                                             const float* __restrict__ Wvr,
                                             const f16* __restrict__ Wq16,
                                             const f16* __restrict__ WoutT,
                                             f16* __restrict__ Wqlt,
                                             f16* __restrict__ W2t) {
  __shared__ f16 sA[64 * 136];
  __shared__ f16 sB[128 * 128];
  const int z = blockIdx.z;
  const int h = blockIdx.y;
  const int d0 = blockIdx.x * 128;
  const float* Wsm = z ? Wvr : Wkr;
  const f16* Bsrc = (z ? WoutT : Wq16) + h * 128;
  const int tid = threadIdx.x;
  const int w = tid >> 6, lane = tid & 63;
  const int quad = lane >> 4, l16 = lane & 15;

#pragma unroll
  for (int it = 0; it < 8; it++) {
    int i = it * 256 + tid;
    float4 f = ((const float4*)Wsm)[i];
    int e = i * 4, r = e >> 7, c = e & 127;
    f16x4 o; o[0] = (f16)f.x; o[1] = (f16)f.y; o[2] = (f16)f.z; o[3] = (f16)f.w;
    *(f16x4*)&sA[r * 136 + c] = o;
  }
#pragma unroll
  for (int c = 0; c < 8; c++) {
    int rbase = w * 32 + c * 4;
    load_lds16(Bsrc + (size_t)(d0 + rbase + (lane >> 4)) * 2048 + (lane & 15) * 8,
               &sB[rbase * 128]);
  }
  __syncthreads();

  if (z == 0) {
    f32x4 acc[4][2];
    for (int mt = 0; mt < 4; mt++)
      for (int nt = 0; nt < 2; nt++) acc[mt][nt] = (f32x4){0.f, 0.f, 0.f, 0.f};
#pragma unroll
    for (int ks = 0; ks < 4; ks++) {
      f16x8 af[4], bf[2];
#pragma unroll
      for (int mt = 0; mt < 4; mt++)
        af[mt] = *(const f16x8*)&sA[(mt * 16 + l16) * 136 + ks * 32 + quad * 8];
#pragma unroll
      for (int nt = 0; nt < 2; nt++)
        bf[nt] = *(const f16x8*)&sB[(w * 32 + nt * 16 + l16) * 128 + ks * 32 + quad * 8];
#pragma unroll
      for (int mt = 0; mt < 4; mt++)
#pragma unroll
        for (int nt = 0; nt < 2; nt++) acc[mt][nt] = mfma16(af[mt], bf[nt], acc[mt][nt]);
    }
#pragma unroll
    for (int mt = 0; mt < 4; mt++)
#pragma unroll
      for (int nt = 0; nt < 2; nt++)
#pragma unroll
        for (int r = 0; r < 4; r++) {
          int row = mt * 16 + quad * 4 + r;
          int col = d0 + w * 32 + nt * 16 + l16;
          Wqlt[(size_t)(h * 64 + row) * 2048 + col] = (f16)acc[mt][nt][r];
        }
  } else {
    f32x4 acc[2][4];
    for (int mt = 0; mt < 2; mt++)
      for (int nt = 0; nt < 4; nt++) acc[mt][nt] = (f32x4){0.f, 0.f, 0.f, 0.f};
#pragma unroll
    for (int ks = 0; ks < 4; ks++) {
      f16x8 af[2], bf[4];
#pragma unroll
      for (int mt = 0; mt < 2; mt++)
        af[mt] = *(const f16x8*)&sB[(w * 32 + mt * 16 + l16) * 128 + ks * 32 + quad * 8];
#pragma unroll
      for (int nt = 0; nt < 4; nt++)
        bf[nt] = *(const f16x8*)&sA[(nt * 16 + l16) * 136 + ks * 32 + quad * 8];
#pragma unroll
      for (int mt = 0; mt < 2; mt++)
#pragma unroll
        for (int nt = 0; nt < 4; nt++) acc[mt][nt] = mfma16(af[mt], bf[nt], acc[mt][nt]);
    }
#pragma unroll
    for (int mt = 0; mt < 2; mt++)
#pragma unroll
      for (int nt = 0; nt < 4; nt++)
#pragma unroll
        for (int r = 0; r < 4; r++) {
          int row = d0 + w * 32 + mt * 16 + quad * 4 + r;
          int col = nt * 16 + l16;
          W2t[(size_t)row * 1024 + h * 64 + col] = (f16)acc[mt][nt][r];
        }
  }
}

// ---------- MFMA GEMM: C[M,N] = A[M,K] @ Bt[N,K]^T (+ bias) ----------
// R6 sync structure (BK=32, 2-phase gload_lds dbuf, 0-conflict within-row chunk
// swizzle) on a 64x128 tile: grid 8x64(x3) = 6 blocks/CU EXACTLY (zero tail),
// LDS 24 KB -> 6 resident -> 24 waves/CU = 6 waves/SIMD (2x the 128x128 config;
// that one was grid-capped at 3 blocks/CU). Staging: 12 groups of 16 rows
// (A:0..3, B:4..11), wave w owns 3; lane i -> local row i>>2, permuted chunk
// (i&3)^((i>>3)&3) (same 64B segments as linear -> coalescing intact; LDS dest
// linear as global_load_lds requires). Fragment read offset is the base-16-
// invariant per-lane constant xoff=(quad^((l16>>1)&3))*8. Per wave: 3 staging
// loads + 6 b128 frag reads + 8 MFMA per K-step. All 4 waves share the A frags.
template <typename OutT, bool HAS_BIAS>
__device__ __forceinline__ void gemm_body(const f16* __restrict__ A, const f16* __restrict__ Bt,
                                          const float* __restrict__ bias, OutT* __restrict__ C,
                                          int N, int K, int m0, int n0) {
  __shared__ f16 sA[2][64 * 32];    // 2 x 4 KB
  __shared__ f16 sB[2][128 * 32];   // 2 x 8 KB
  const int tid = threadIdx.x;
  const int w = tid >> 6, lane = tid & 63;
  const int quad = lane >> 4, l16 = lane & 15;

  // staging: 12 groups of 16 rows; wave w owns groups [w*3, w*3+3).
  const int srow = lane >> 2;
  const int schunk = (lane & 3) ^ ((lane >> 3) & 3);
  const f16* gsrc[3];
  int loff[3];
  bool ia[3];
#pragma unroll
  for (int c = 0; c < 3; c++) {
    int gi = w * 3 + c;
    ia[c] = gi < 4;
    gsrc[c] = ia[c] ? A + (size_t)(m0 + gi * 16 + srow) * K + schunk * 8
                    : Bt + (size_t)(n0 + (gi - 4) * 16 + srow) * K + schunk * 8;
    loff[c] = ia[c] ? gi * 512 : (gi - 4) * 512;
  }

  // fragment read: slot = row*4 + (quad ^ ((row>>1)&3)); row base terms vanish.
  const int xoff = (quad ^ ((l16 >> 1) & 3)) * 8;

  f32x4 acc[4][2];
#pragma unroll
  for (int i = 0; i < 4; i++)
#pragma unroll
    for (int j = 0; j < 2; j++) acc[i][j] = (f32x4){0.f, 0.f, 0.f, 0.f};

  // prologue: stage k0=0 into buffer 0
#pragma unroll
  for (int c = 0; c < 3; c++)
    load_lds16(gsrc[c], (ia[c] ? &sA[0][0] : &sB[0][0]) + loff[c]);
  int cur = 0;

  for (int k0 = 0; k0 < K; k0 += 32) {
    __syncthreads();  // buf[cur] staged; buf[cur^1] readers from prev iter done
    if (k0 + 32 < K) {
#pragma unroll
      for (int c = 0; c < 3; c++)
        load_lds16(gsrc[c] + k0 + 32, (ia[c] ? &sA[cur ^ 1][0] : &sB[cur ^ 1][0]) + loff[c]);
    }
    const f16* sAc = &sA[cur][0];
    const f16* sBc = &sB[cur][0];
    f16x8 af[4], bfr[2];
#pragma unroll
    for (int mt = 0; mt < 4; mt++)
      af[mt] = *(const f16x8*)&sAc[(mt * 16 + l16) * 32 + xoff];
#pragma unroll
    for (int nt = 0; nt < 2; nt++)
      bfr[nt] = *(const f16x8*)&sBc[(w * 32 + nt * 16 + l16) * 32 + xoff];
#pragma unroll
    for (int mt = 0; mt < 4; mt++) {
#pragma unroll
      for (int nt = 0; nt < 2; nt++)
        acc[mt][nt] = mfma16(af[mt], bfr[nt], acc[mt][nt]);
    }
    cur ^= 1;
  }
#pragma unroll
  for (int mt = 0; mt < 4; mt++) {
#pragma unroll
    for (int nt = 0; nt < 2; nt++) {
      int col = n0 + w * 32 + nt * 16 + l16;
      float bv = HAS_BIAS ? bias[col] : 0.f;
#pragma unroll
      for (int r = 0; r < 4; r++) {
        int row = m0 + mt * 16 + quad * 4 + r;
        C[(size_t)row * N + col] = (OutT)(acc[mt][nt][r] + bv);
      }
    }
  }
}

// XCD-aware swizzle within a slice of nwg blocks (nwg % 8 == 0): physical block
// `flat` lands on XCD flat%8; give that XCD the contiguous work chunk
// [xcd*nwg/8, ...), x-fastest so chunk-mates share A row-panels in their L2.
__device__ __forceinline__ int xcd_swizzle(int flat, int nwg) {
  const int cpx = nwg >> 3;
  return (flat & 7) * cpx + (flat >> 3);
}

__global__ __launch_bounds__(256, 6) void gemm3_f16(
    const f16* __restrict__ A0, const f16* __restrict__ A1, const f16* __restrict__ A2,
    const f16* __restrict__ B0, const f16* __restrict__ B1, const f16* __restrict__ B2,
    const float* __restrict__ c0, const float* __restrict__ c1, const float* __restrict__ c2,
    f16* __restrict__ C0, f16* __restrict__ C1, f16* __restrict__ C2, int N, int K) {
  const f16* A = blockIdx.z == 0 ? A0 : blockIdx.z == 1 ? A1 : A2;
  const f16* Bt = blockIdx.z == 0 ? B0 : blockIdx.z == 1 ? B1 : B2;
  const float* bias = blockIdx.z == 0 ? c0 : blockIdx.z == 1 ? c1 : c2;
  f16* C = blockIdx.z == 0 ? C0 : blockIdx.z == 1 ? C1 : C2;
  const int nx = gridDim.x;
  int swz = xcd_swizzle(blockIdx.y * nx + blockIdx.x, nx * gridDim.y);
  gemm_body<f16, true>(A, Bt, bias, C, N, K, (swz / nx) * 64, (swz % nx) * 128);
}

__global__ __launch_bounds__(256, 6) void gemm_f32(const f16* __restrict__ A,
                                                   const f16* __restrict__ Bt,
                                                   const float* __restrict__ bias,
                                                   float* __restrict__ C, int N, int K) {
  const int nx = gridDim.x;
  int swz = xcd_swizzle(blockIdx.y * nx + blockIdx.x, nx * gridDim.y);
  gemm_body<float, true>(A, Bt, bias, C, N, K, (swz / nx) * 64, (swz % nx) * 128);
}

// ---------- LDS-tiled transpose: LV[(b,s)][(h,l)] -> LVt[(b,h)][l][s] ----------
__global__ __launch_bounds__(256) void transpose_lv(const f16* __restrict__ LV,
                                                    f16* __restrict__ LVt) {
  const int bh = blockIdx.y, b = bh >> 4, h = bh & 15;
  const int s0 = blockIdx.x * 64;
  __shared__ f16 tile[64][65];
  const int t = threadIdx.x;
  const int c0 = t & 63, r0 = t >> 6;
#pragma unroll
  for (int r = 0; r < 16; r++) {
    int s = r * 4 + r0;
    tile[s][c0] = LV[(size_t)(b * kS + s0 + s) * kHL + h * kL + c0];
  }
  __syncthreads();
#pragma unroll
  for (int r = 0; r < 16; r++) {
    int vl = r * 4 + r0;
    LVt[((size_t)bh * kL + vl) * kS + s0 + c0] = tile[c0][vl];
  }
}

// ---------- latent flash attention ----------
// Swapped QK^T: sc[nt] = mfma(A=K-frag, B=Q-frag) so each lane's scores are
//   score(q = q0 + w*16 + l16, kv = kv0 + nt*16 + quad*4 + r)
// -> row max/sum are in-lane trees + 2 shfl_xor (16,32) instead of 4-deep chains,
//    P values are kv-contiguous per lane (one ds_write_b64 per nt),
//    one exp2+fma per element, deferred alpha-rescale (skip when max didn't grow),
//    K/V LDS double-buffered with one barrier per tile (prefetch overlaps compute),
//    s_setprio(1) around MFMA clusters (T5: independent blocks at different phases).
__global__ __launch_bounds__(256) void attn(const f16* __restrict__ Qlat,
                                            const f16* __restrict__ LK,
                                            const f16* __restrict__ LVt,
                                            f16* __restrict__ Ctx) {
  const int bh = blockIdx.y, b = bh >> 4, h = bh & 15;
  const int pair = blockIdx.x;  // 0..15
  const int tid = threadIdx.x;
  const int w = tid >> 6, lane = tid & 63;
  const int quad = lane >> 4, l16 = lane & 15;

  __shared__ f16 sK[2][64 * 64];  // [kv][l], swizzled chunks, double-buffered
  __shared__ f16 sV[2][64 * 64];  // [vl][kv], swizzled chunks, double-buffered
  __shared__ f16 sP[4][16 * 72];  // per-wave P tile [q][kv], stride 72

  const f16* qbase = Qlat + (size_t)b * kS * kHL + h * kL;
  const f16* kbase = LK + (size_t)b * kS * kHL + h * kL;
  const f16* vbase = LVt + (size_t)bh * kL * kS;

  // scale * log2(e): scores kept raw until the exp2; p = exp2(sc*cscale - m)
  const float cscale = 0.08838834764831845f * 1.4426950408889634f;
  const int rowA = lane >> 3;
  const int colSw = (((lane & 7) ^ (lane >> 3)) << 3);
  const int sw0 = ((quad ^ (l16 & 7)) << 3);
  const int sw1 = (((4 + quad) ^ (l16 & 7)) << 3);

  for (int which = 0; which < 2; which++) {
    const int t = which ? (31 - pair) : pair;
    const int q0 = t * 64;
    const int qrow = q0 + w * 16 + l16;
    const int qg = qrow;  // this lane's q row (softmax domain)
    const int ntile = t + 1;

    f16x8 aq[2];
#pragma unroll
    for (int ks = 0; ks < 2; ks++)
      aq[ks] = *(const f16x8*)(qbase + (size_t)qrow * kHL + ks * 32 + quad * 8);

    f32x4 acc[4];
    for (int nt = 0; nt < 4; nt++) acc[nt] = (f32x4){0.f, 0.f, 0.f, 0.f};
    float m_s = -3.0e38f;   // running row max, scaled-log2 domain (row l16)
    float l_part = 0.f;     // per-lane partial row sum (this lane's kv subset)

    // prologue: stage tile 0 into buffer 0
    __syncthreads();  // previous 'which' readers done before overwriting LDS
    {
      const int rl = w * 16;
      load_lds16(kbase + (size_t)(rl + rowA) * kHL + colSw, &sK[0][rl * 64]);
      load_lds16(vbase + (size_t)(rl + rowA) * kS + colSw, &sV[0][rl * 64]);
      load_lds16(kbase + (size_t)(rl + 8 + rowA) * kHL + colSw, &sK[0][(rl + 8) * 64]);
      load_lds16(vbase + (size_t)(rl + 8 + rowA) * kS + colSw, &sV[0][(rl + 8) * 64]);
    }
    int cur = 0;

    for (int it = 0; it < ntile; ++it) {
      const int kv0 = it * 64;
      __syncthreads();  // staging of buf[cur] drained (vmcnt before barrier)

      if (it + 1 < ntile) {  // prefetch next tile into the other buffer
        const int nkv = kv0 + 64;
        f16* dK = &sK[cur ^ 1][0];
        f16* dV = &sV[cur ^ 1][0];
        const int rl = w * 16;
        load_lds16(kbase + (size_t)(nkv + rl + rowA) * kHL + colSw, dK + rl * 64);
        load_lds16(vbase + (size_t)(rl + rowA) * kS + nkv + colSw, dV + rl * 64);
        load_lds16(kbase + (size_t)(nkv + rl + 8 + rowA) * kHL + colSw, dK + (rl + 8) * 64);
        load_lds16(vbase + (size_t)(rl + 8 + rowA) * kS + nkv + colSw, dV + (rl + 8) * 64);
      }
      const f16* sKc = &sK[cur][0];
      const f16* sVc = &sV[cur][0];

      // QK^T (swapped operands): lane holds q-row l16, kv = nt*16 + quad*4 + r
      f32x4 sc[4];
      for (int nt = 0; nt < 4; nt++) sc[nt] = (f32x4){0.f, 0.f, 0.f, 0.f};
#pragma unroll
      for (int ks = 0; ks < 2; ks++) {
        const int sw = ks ? sw1 : sw0;
        f16x8 bk[4];
#pragma unroll
        for (int nt = 0; nt < 4; nt++)
          bk[nt] = *(const f16x8*)&sKc[(nt * 16 + l16) * 64 + sw];
        __builtin_amdgcn_s_setprio(1);
#pragma unroll
        for (int nt = 0; nt < 4; nt++) sc[nt] = mfma16(bk[nt], aq[ks], sc[nt]);
        __builtin_amdgcn_s_setprio(0);
      }

      if (kv0 == q0) {  // diagonal tile: causal mask (raw domain)
#pragma unroll
        for (int nt = 0; nt < 4; nt++) {
#pragma unroll
          for (int r = 0; r < 4; r++) {
            int kvg = kv0 + nt * 16 + quad * 4 + r;
            if (kvg > qg) sc[nt][r] = -1.0e30f;
          }
        }
      }

      // in-lane row max + 2-step cross-quad reduce
      float tm = -3.0e38f;
#pragma unroll
      for (int nt = 0; nt < 4; nt++)
        tm = fmaxf(tm, fmaxf(fmaxf(sc[nt][0], sc[nt][1]), fmaxf(sc[nt][2], sc[nt][3])));
      tm = fmaxf(tm, __shfl_xor(tm, 16));
      tm = fmaxf(tm, __shfl_xor(tm, 32));
      const float tms = tm * cscale;

      if (!__all(tms <= m_s)) {  // some row's max grew: rescale (rare after warmup)
        const float mnew = fmaxf(m_s, tms);
        const float alpha = __builtin_amdgcn_exp2f(m_s - mnew);
        m_s = mnew;
        l_part *= alpha;
        float ar[4];
#pragma unroll
        for (int r = 0; r < 4; r++) ar[r] = __shfl(alpha, quad * 4 + r);
#pragma unroll
        for (int nt = 0; nt < 4; nt++)
#pragma unroll
          for (int r = 0; r < 4; r++) acc[nt][r] *= ar[r];
      }

      // p = exp2(sc*cscale - m); pack 4 kv-contiguous values per nt, one b64 write
      float ps = 0.f;
#pragma unroll
      for (int nt = 0; nt < 4; nt++) {
        f16x4 pk;
#pragma unroll
        for (int r = 0; r < 4; r++) {
          float p = __builtin_amdgcn_exp2f(__builtin_fmaf(sc[nt][r], cscale, -m_s));
          ps += p;
          pk[r] = (f16)p;
        }
        *(f16x4*)&sP[w][l16 * 72 + nt * 16 + quad * 4] = pk;
      }
      l_part += ps;

      // PV: A = P (rows = q), B = V (rows = vl) -> acc rows = q (quad*4+r), cols = vl
#pragma unroll
      for (int ks = 0; ks < 2; ks++) {
        const int sw = ks ? sw1 : sw0;
        f16x8 ap = *(const f16x8*)&sP[w][l16 * 72 + ks * 32 + quad * 8];
        f16x8 bv[4];
#pragma unroll
        for (int nt = 0; nt < 4; nt++)
          bv[nt] = *(const f16x8*)&sVc[(nt * 16 + l16) * 64 + sw];
        __builtin_amdgcn_s_setprio(1);
#pragma unroll
        for (int nt = 0; nt < 4; nt++) acc[nt] = mfma16(ap, bv[nt], acc[nt]);
        __builtin_amdgcn_s_setprio(0);
      }
      cur ^= 1;
    }

    // epilogue: finish deferred l reduction, broadcast to acc rows, normalize
    float lfull = l_part;
    lfull += __shfl_xor(lfull, 16);
    lfull += __shfl_xor(lfull, 32);
    float inv[4];
#pragma unroll
    for (int r = 0; r < 4; r++) inv[r] = 1.f / __shfl(lfull, quad * 4 + r);
#pragma unroll
    for (int r = 0; r < 4; r++) {
      int qout = q0 + w * 16 + quad * 4 + r;
      size_t base = (size_t)(b * kS + qout) * kHL + h * kL;
#pragma unroll
      for (int nt = 0; nt < 4; nt++)
        Ctx[base + nt * 16 + l16] = (f16)(acc[nt][r] * inv[r]);
    }
  }
}

extern "C" void kernel_launch(void* const* d_in, const int* in_sizes, int n_in,
                              void* d_out, int out_size, void* d_ws, size_t ws_size,
                              hipStream_t stream) {
  (void)in_sizes; (void)n_in; (void)out_size; (void)ws_size;
  const float* queries = (const float*)d_in[0];
  const float* keys    = (const float*)d_in[1];
  const float* values  = (const float*)d_in[2];
  const float* Wq      = (const float*)d_in[3];
  const float* bq      = (const float*)d_in[4];
  const float* Wlk     = (const float*)d_in[5];
  const float* blk     = (const float*)d_in[6];
  const float* Wlv     = (const float*)d_in[7];
  const float* blv     = (const float*)d_in[8];
  const float* Wkr     = (const float*)d_in[9];
  const float* Wvr     = (const float*)d_in[10];
  const float* Wout    = (const float*)d_in[11];
  const float* bout    = (const float*)d_in[12];

  char* ws = (char*)d_ws;
  size_t off = 0;
  auto alloc = [&](size_t bytes) {
    void* p = ws + off;
    off += (bytes + 255) & ~(size_t)255;
    return p;
  };
  f16* qb    = (f16*)alloc((size_t)kBS * kD * 2);
  f16* kb    = (f16*)alloc((size_t)kBS * kD * 2);
  f16* vb    = (f16*)alloc((size_t)kBS * kD * 2);
  f16* Wqlt  = (f16*)alloc((size_t)kHL * kD * 2);
  f16* Wlkt  = (f16*)alloc((size_t)kHL * kD * 2);
  f16* Wlvt  = (f16*)alloc((size_t)kHL * kD * 2);
  f16* W2t   = (f16*)alloc((size_t)kD * kHL * 2);
  float* bql = (float*)alloc(kHL * 4);
  f16* Qlat  = (f16*)alloc((size_t)kBS * kHL * 2);
  f16* LKb   = (f16*)alloc((size_t)kBS * kHL * 2);
  f16* LVb   = (f16*)alloc((size_t)kBS * kHL * 2);
  // prep-only buffers alias post-fold intermediates (dead by the time those are written):
  f16* Wq16  = Qlat;   // 8 MB (kD*kD f16), consumed by fold2 before gemm3 writes Qlat
  f16* WoutT = LKb;    // 8 MB, consumed by fold2 before gemm3 writes LKb
  // input-cast buffers alias post-attn intermediates:
  f16* LVtb = qb;  // LV transposed [b,h][l][s] — qb dead after gemm3
  f16* Ctx  = kb;  // attention output — kb dead after gemm3

  const int n4 = kBS * kD / 4;  // 2M float4 per q/k/v tensor
  cast4<<<dim3(n4 / 256, 1, 4), 256, 0, stream>>>(queries, keys, values, Wq, qb, kb, vb, Wq16);
  transpose3<<<dim3(32, 32, 3), 256, 0, stream>>>(Wlk, Wlv, Wout, Wlkt, Wlvt, WoutT);
  fold_bq<<<kHL / 256, 256, 0, stream>>>(bq, Wkr, bql);
  fold2<<<dim3(16, 16, 2), 256, 0, stream>>>(Wkr, Wvr, Wq16, WoutT, Wqlt, W2t);

  gemm3_f16<<<dim3(kHL / 128, kBS / 64, 3), 256, 0, stream>>>(
      qb, kb, vb, Wqlt, Wlkt, Wlvt, bql, blk, blv, Qlat, LKb, LVb, kHL, kD);

  transpose_lv<<<dim3(kS / 64, kB * kH), 256, 0, stream>>>(LVb, LVtb);
  attn<<<dim3(16, kB * kH), 256, 0, stream>>>(Qlat, LKb, LVtb, Ctx);
  gemm_f32<<<dim3(kD / 128, kBS / 64), 256, 0, stream>>>(Ctx, W2t, bout, (float*)d_out, kD, kHL);
}

// Round 14
// 355.373 us; speedup vs baseline: 1.0551x; 1.0551x over previous
//
#include <hip/hip_runtime.h>
#include <cstdint>
#include <cstddef>

typedef _Float16 f16;
typedef __attribute__((ext_vector_type(8))) _Float16 f16x8;
typedef __attribute__((ext_vector_type(4))) _Float16 f16x4;
typedef __attribute__((ext_vector_type(4))) float f32x4;

constexpr int kB  = 2;
constexpr int kS  = 2048;
constexpr int kD  = 2048;
constexpr int kH  = 16;
constexpr int kL  = 64;
constexpr int kHL = kH * kL;   // 1024
constexpr int kBS = kB * kS;   // 4096

__device__ __forceinline__ void load_lds16(const void* g, void* l) {
  __builtin_amdgcn_global_load_lds((const __attribute__((address_space(1))) void*)g,
                                   (__attribute__((address_space(3))) void*)l, 16, 0, 0);
}

__device__ __forceinline__ f32x4 mfma16(f16x8 a, f16x8 b, f32x4 c) {
  return __builtin_amdgcn_mfma_f32_16x16x32_f16(a, b, c, 0, 0, 0);
}

// ---------- merged fp32 -> fp16 cast: z=0..2 q/k/v (8M elems), z=3 Wq (4M elems) ----------
__global__ void cast4(const float* __restrict__ a, const float* __restrict__ b,
                      const float* __restrict__ c, const float* __restrict__ d,
                      f16* __restrict__ oa, f16* __restrict__ ob,
                      f16* __restrict__ oc, f16* __restrict__ od) {
  const int z = blockIdx.z;
  int i = blockIdx.x * 256 + threadIdx.x;
  if (z == 3 && i >= kD * kD / 4) return;
  const float* in = z == 0 ? a : z == 1 ? b : z == 2 ? c : d;
  f16* out = z == 0 ? oa : z == 1 ? ob : z == 2 ? oc : od;
  float4 f = ((const float4*)in)[i];
  f16x4 o; o[0] = (f16)f.x; o[1] = (f16)f.y; o[2] = (f16)f.z; o[3] = (f16)f.w;
  ((f16x4*)out)[i] = o;
}

// ---------- LDS-tiled transpose-cast: in[R][C] fp32 -> out[C][R] fp16 ----------
__device__ __forceinline__ void transpose_body(const float* __restrict__ in,
                                               f16* __restrict__ out, int R, int C) {
  const int r0 = blockIdx.y * 64, c0 = blockIdx.x * 64;
  __shared__ float tile[64][65];
  const int t = threadIdx.x;
  const int cc = t & 63, rr = t >> 6;
#pragma unroll
  for (int p = 0; p < 16; p++) {
    int r = p * 4 + rr;
    tile[r][cc] = in[(size_t)(r0 + r) * C + c0 + cc];
  }
  __syncthreads();
#pragma unroll
  for (int p = 0; p < 16; p++) {
    int c = p * 4 + rr;
    out[(size_t)(c0 + c) * R + r0 + cc] = (f16)tile[cc][c];
  }
}

// z=0: Wlk [2048][1024]->[1024][2048] ; z=1: Wlv same ; z=2: Wout [2048][2048] transposed
__global__ __launch_bounds__(256) void transpose3(const float* __restrict__ Wlk,
                                                  const float* __restrict__ Wlv,
                                                  const float* __restrict__ Wout,
                                                  f16* __restrict__ Wlkt,
                                                  f16* __restrict__ Wlvt,
                                                  f16* __restrict__ WoutT) {
  const int z = blockIdx.z;
  if (z < 2 && blockIdx.x >= 16) return;
  if (z == 0) transpose_body(Wlk, Wlkt, 2048, 1024);
  else if (z == 1) transpose_body(Wlv, Wlvt, 2048, 1024);
  else transpose_body(Wout, WoutT, 2048, 2048);
}

__global__ void fold_bq(const float* __restrict__ bq, const float* __restrict__ Wkr,
                        float* __restrict__ bql) {
  int hl = blockIdx.x * 256 + threadIdx.x;
  if (hl >= kHL) return;
  int h = hl >> 6, l = hl & 63;
  float s = 0.f;
  for (int c = 0; c < 128; c++) s += bq[h * 128 + c] * Wkr[l * 128 + c];
  bql[hl] = s;
}

// ---------- direct per-head fold GEMMs ----------
// z=0: Wqlt[h*64+l][d]  = sum_c Wkr[l][c] * Wq16 [d][h*128+c]   (tile 64 x 128)
// z=1: W2t [d][h*64+l]  = sum_c Wvr[l][c] * WoutT[d][h*128+c]   (tile 128 x 64)
__global__ __launch_bounds__(256) void fold2(const float* __restrict__ Wkr,
                                             const float* __restrict__ Wvr,
                                             const f16* __restrict__ Wq16,
                                             const f16* __restrict__ WoutT,
                                             f16* __restrict__ Wqlt,
                                             f16* __restrict__ W2t) {
  __shared__ f16 sA[64 * 136];
  __shared__ f16 sB[128 * 128];
  const int z = blockIdx.z;
  const int h = blockIdx.y;
  const int d0 = blockIdx.x * 128;
  const float* Wsm = z ? Wvr : Wkr;
  const f16* Bsrc = (z ? WoutT : Wq16) + h * 128;
  const int tid = threadIdx.x;
  const int w = tid >> 6, lane = tid & 63;
  const int quad = lane >> 4, l16 = lane & 15;

#pragma unroll
  for (int it = 0; it < 8; it++) {
    int i = it * 256 + tid;
    float4 f = ((const float4*)Wsm)[i];
    int e = i * 4, r = e >> 7, c = e & 127;
    f16x4 o; o[0] = (f16)f.x; o[1] = (f16)f.y; o[2] = (f16)f.z; o[3] = (f16)f.w;
    *(f16x4*)&sA[r * 136 + c] = o;
  }
#pragma unroll
  for (int c = 0; c < 8; c++) {
    int rbase = w * 32 + c * 4;
    load_lds16(Bsrc + (size_t)(d0 + rbase + (lane >> 4)) * 2048 + (lane & 15) * 8,
               &sB[rbase * 128]);
  }
  __syncthreads();

  if (z == 0) {
    f32x4 acc[4][2];
    for (int mt = 0; mt < 4; mt++)
      for (int nt = 0; nt < 2; nt++) acc[mt][nt] = (f32x4){0.f, 0.f, 0.f, 0.f};
#pragma unroll
    for (int ks = 0; ks < 4; ks++) {
      f16x8 af[4], bf[2];
#pragma unroll
      for (int mt = 0; mt < 4; mt++)
        af[mt] = *(const f16x8*)&sA[(mt * 16 + l16) * 136 + ks * 32 + quad * 8];
#pragma unroll
      for (int nt = 0; nt < 2; nt++)
        bf[nt] = *(const f16x8*)&sB[(w * 32 + nt * 16 + l16) * 128 + ks * 32 + quad * 8];
#pragma unroll
      for (int mt = 0; mt < 4; mt++)
#pragma unroll
        for (int nt = 0; nt < 2; nt++) acc[mt][nt] = mfma16(af[mt], bf[nt], acc[mt][nt]);
    }
#pragma unroll
    for (int mt = 0; mt < 4; mt++)
#pragma unroll
      for (int nt = 0; nt < 2; nt++)
#pragma unroll
        for (int r = 0; r < 4; r++) {
          int row = mt * 16 + quad * 4 + r;
          int col = d0 + w * 32 + nt * 16 + l16;
          Wqlt[(size_t)(h * 64 + row) * 2048 + col] = (f16)acc[mt][nt][r];
        }
  } else {
    f32x4 acc[2][4];
    for (int mt = 0; mt < 2; mt++)
      for (int nt = 0; nt < 4; nt++) acc[mt][nt] = (f32x4){0.f, 0.f, 0.f, 0.f};
#pragma unroll
    for (int ks = 0; ks < 4; ks++) {
      f16x8 af[2], bf[4];
#pragma unroll
      for (int mt = 0; mt < 2; mt++)
        af[mt] = *(const f16x8*)&sB[(w * 32 + mt * 16 + l16) * 128 + ks * 32 + quad * 8];
#pragma unroll
      for (int nt = 0; nt < 4; nt++)
        bf[nt] = *(const f16x8*)&sA[(nt * 16 + l16) * 136 + ks * 32 + quad * 8];
#pragma unroll
      for (int mt = 0; mt < 2; mt++)
#pragma unroll
        for (int nt = 0; nt < 4; nt++) acc[mt][nt] = mfma16(af[mt], bf[nt], acc[mt][nt]);
    }
#pragma unroll
    for (int mt = 0; mt < 2; mt++)
#pragma unroll
      for (int nt = 0; nt < 4; nt++)
#pragma unroll
        for (int r = 0; r < 4; r++) {
          int row = d0 + w * 32 + mt * 16 + quad * 4 + r;
          int col = nt * 16 + l16;
          W2t[(size_t)row * 1024 + h * 64 + col] = (f16)acc[mt][nt][r];
        }
  }
}

// ---------- MFMA GEMM: C[M,N] = A[M,K] @ Bt[N,K]^T (+ bias) ----------
// SESSION-BEST, final (R6/R10/R12, measured 70.3-70.9 us, MfmaUtil ~30,
// 0 bank conflicts, occupancy ~29%): 128x128 tile, BK=32, 2-phase
// global_load_lds double-buffer, 32 KiB LDS -> 3 blocks/CU, all 768 blocks
// co-resident. Bank-conflict fix via WITHIN-ROW chunk swizzle: logical chunk c
// of tile row r lives at slot r*4 + (c ^ ((r>>1)&3)). Staging lane i sources
// global chunk (i&3)^((i>>3)&3) of row i>>2 -> same 64B segments as linear
// (coalescing preserved); LDS dest stays linear (global_load_lds requirement).
// Fragment-read offset folds to the per-lane constant xoff=(quad^((l16>>1)&3))*8.
// Structural A/B history (all counter-verified, all worse): BK=64 XOR 2-barrier
// (R1 82us), 64KB dbuf (R2 78us, occupancy collapse), chunk-major global
// scatter (R4 105us, uncoalesced), reg-staged T14 (R5 79us), 3-deep counted
// vmcnt (R7 72us), 8-phase x8 MFMA (R8 105us), 2-phase x16 MFMA 256-tile
// (R9 78us), fused fp32-A (R11 130us), 64x128 tile (R13 93us: MFMA-per-barrier
// halved; occupancy is not the lever, MFMA-per-barrier-interval is).
template <typename OutT, bool HAS_BIAS>
__device__ __forceinline__ void gemm_body(const f16* __restrict__ A, const f16* __restrict__ Bt,
                                          const float* __restrict__ bias, OutT* __restrict__ C,
                                          int N, int K, int m0, int n0) {
  __shared__ f16 sA[2][128 * 32];
  __shared__ f16 sB[2][128 * 32];
  const int tid = threadIdx.x;
  const int w = tid >> 6, lane = tid & 63;
  const int quad = lane >> 4, l16 = lane & 15;
  const int wm = w >> 1, wn = w & 1;

  // staging: wave w covers rows [w*32, w*32+32) as two 16-row groups.
  // lane i -> local row i>>2, permuted chunk (i&3)^((i>>3)&3).
  const int srow = lane >> 2;
  const int schunk = (lane & 3) ^ ((lane >> 3) & 3);
  const f16* aptr = A + (size_t)(m0 + w * 32 + srow) * K + schunk * 8;
  const f16* bptr = Bt + (size_t)(n0 + w * 32 + srow) * K + schunk * 8;
  const int g0 = w * 1024;   // f16 index of wave's first 16-row group (1 KB)
  const int g1 = g0 + 512;

  // fragment read: slot = row*4 + (quad ^ ((row>>1)&3)); row terms vanish mod 4.
  const int xoff = (quad ^ ((l16 >> 1) & 3)) * 8;

  f32x4 acc[4][4];
  for (int i = 0; i < 4; i++)
    for (int j = 0; j < 4; j++) acc[i][j] = (f32x4){0.f, 0.f, 0.f, 0.f};

  // prologue: stage k0=0 into buffer 0
  load_lds16(aptr, &sA[0][g0]);
  load_lds16(aptr + (size_t)16 * K, &sA[0][g1]);
  load_lds16(bptr, &sB[0][g0]);
  load_lds16(bptr + (size_t)16 * K, &sB[0][g1]);
  int cur = 0;

  for (int k0 = 0; k0 < K; k0 += 32) {
    __syncthreads();  // buf[cur] staged; buf[cur^1] readers from prev iter done
    if (k0 + 32 < K) {
      const f16* ap = aptr + k0 + 32;
      const f16* bp = bptr + k0 + 32;
      f16* dA = &sA[cur ^ 1][0];
      f16* dB = &sB[cur ^ 1][0];
      load_lds16(ap, dA + g0);
      load_lds16(ap + (size_t)16 * K, dA + g1);
      load_lds16(bp, dB + g0);
      load_lds16(bp + (size_t)16 * K, dB + g1);
    }
    const f16* sAc = &sA[cur][0];
    const f16* sBc = &sB[cur][0];
    f16x8 af[4], bfr[4];
#pragma unroll
    for (int mt = 0; mt < 4; mt++)
      af[mt] = *(const f16x8*)&sAc[(wm * 64 + mt * 16 + l16) * 32 + xoff];
#pragma unroll
    for (int nt = 0; nt < 4; nt++)
      bfr[nt] = *(const f16x8*)&sBc[(wn * 64 + nt * 16 + l16) * 32 + xoff];
#pragma unroll
    for (int mt = 0; mt < 4; mt++) {
#pragma unroll
      for (int nt = 0; nt < 4; nt++)
        acc[mt][nt] = mfma16(af[mt], bfr[nt], acc[mt][nt]);
    }
    cur ^= 1;
  }
#pragma unroll
  for (int mt = 0; mt < 4; mt++) {
#pragma unroll
    for (int nt = 0; nt < 4; nt++) {
      int col = n0 + wn * 64 + nt * 16 + l16;
      float bv = HAS_BIAS ? bias[col] : 0.f;
#pragma unroll
      for (int r = 0; r < 4; r++) {
        int row = m0 + wm * 64 + mt * 16 + quad * 4 + r;
        C[(size_t)row * N + col] = (OutT)(acc[mt][nt][r] + bv);
      }
    }
  }
}

// XCD-aware swizzle within a slice of nwg blocks (nwg % 8 == 0): physical block
// `flat` lands on XCD flat%8; give that XCD the contiguous work chunk
// [xcd*nwg/8, ...), x-fastest so chunk-mates share A row-panels in their L2.
__device__ __forceinline__ int xcd_swizzle(int flat, int nwg) {
  const int cpx = nwg >> 3;
  return (flat & 7) * cpx + (flat >> 3);
}

__global__ __launch_bounds__(256) void gemm3_f16(
    const f16* __restrict__ A0, const f16* __restrict__ A1, const f16* __restrict__ A2,
    const f16* __restrict__ B0, const f16* __restrict__ B1, const f16* __restrict__ B2,
    const float* __restrict__ c0, const float* __restrict__ c1, const float* __restrict__ c2,
    f16* __restrict__ C0, f16* __restrict__ C1, f16* __restrict__ C2, int N, int K) {
  const f16* A = blockIdx.z == 0 ? A0 : blockIdx.z == 1 ? A1 : A2;
  const f16* Bt = blockIdx.z == 0 ? B0 : blockIdx.z == 1 ? B1 : B2;
  const float* bias = blockIdx.z == 0 ? c0 : blockIdx.z == 1 ? c1 : c2;
  f16* C = blockIdx.z == 0 ? C0 : blockIdx.z == 1 ? C1 : C2;
  const int nx = gridDim.x;
  int swz = xcd_swizzle(blockIdx.y * nx + blockIdx.x, nx * gridDim.y);
  gemm_body<f16, true>(A, Bt, bias, C, N, K, (swz / nx) * 128, (swz % nx) * 128);
}

__global__ __launch_bounds__(256) void gemm_f32(const f16* __restrict__ A,
                                                const f16* __restrict__ Bt,
                                                const float* __restrict__ bias,
                                                float* __restrict__ C, int N, int K) {
  const int nx = gridDim.x;
  int swz = xcd_swizzle(blockIdx.y * nx + blockIdx.x, nx * gridDim.y);
  gemm_body<float, true>(A, Bt, bias, C, N, K, (swz / nx) * 128, (swz % nx) * 128);
}

// ---------- LDS-tiled transpose: LV[(b,s)][(h,l)] -> LVt[(b,h)][l][s] ----------
__global__ __launch_bounds__(256) void transpose_lv(const f16* __restrict__ LV,
                                                    f16* __restrict__ LVt) {
  const int bh = blockIdx.y, b = bh >> 4, h = bh & 15;
  const int s0 = blockIdx.x * 64;
  __shared__ f16 tile[64][65];
  const int t = threadIdx.x;
  const int c0 = t & 63, r0 = t >> 6;
#pragma unroll
  for (int r = 0; r < 16; r++) {
    int s = r * 4 + r0;
    tile[s][c0] = LV[(size_t)(b * kS + s0 + s) * kHL + h * kL + c0];
  }
  __syncthreads();
#pragma unroll
  for (int r = 0; r < 16; r++) {
    int vl = r * 4 + r0;
    LVt[((size_t)bh * kL + vl) * kS + s0 + c0] = tile[c0][vl];
  }
}

// ---------- latent flash attention ----------
// Swapped QK^T: sc[nt] = mfma(A=K-frag, B=Q-frag) so each lane's scores are
//   score(q = q0 + w*16 + l16, kv = kv0 + nt*16 + quad*4 + r)
// -> row max/sum are in-lane trees + 2 shfl_xor (16,32) instead of 4-deep chains,
//    P values are kv-contiguous per lane (one ds_write_b64 per nt),
//    one exp2+fma per element, deferred alpha-rescale (skip when max didn't grow),
//    K/V LDS double-buffered with one barrier per tile (prefetch overlaps compute),
//    s_setprio(1) around MFMA clusters (T5: independent blocks at different phases).
__global__ __launch_bounds__(256) void attn(const f16* __restrict__ Qlat,
                                            const f16* __restrict__ LK,
                                            const f16* __restrict__ LVt,
                                            f16* __restrict__ Ctx) {
  const int bh = blockIdx.y, b = bh >> 4, h = bh & 15;
  const int pair = blockIdx.x;  // 0..15
  const int tid = threadIdx.x;
  const int w = tid >> 6, lane = tid & 63;
  const int quad = lane >> 4, l16 = lane & 15;

  __shared__ f16 sK[2][64 * 64];  // [kv][l], swizzled chunks, double-buffered
  __shared__ f16 sV[2][64 * 64];  // [vl][kv], swizzled chunks, double-buffered
  __shared__ f16 sP[4][16 * 72];  // per-wave P tile [q][kv], stride 72

  const f16* qbase = Qlat + (size_t)b * kS * kHL + h * kL;
  const f16* kbase = LK + (size_t)b * kS * kHL + h * kL;
  const f16* vbase = LVt + (size_t)bh * kL * kS;

  // scale * log2(e): scores kept raw until the exp2; p = exp2(sc*cscale - m)
  const float cscale = 0.08838834764831845f * 1.4426950408889634f;
  const int rowA = lane >> 3;
  const int colSw = (((lane & 7) ^ (lane >> 3)) << 3);
  const int sw0 = ((quad ^ (l16 & 7)) << 3);
  const int sw1 = (((4 + quad) ^ (l16 & 7)) << 3);

  for (int which = 0; which < 2; which++) {
    const int t = which ? (31 - pair) : pair;
    const int q0 = t * 64;
    const int qrow = q0 + w * 16 + l16;
    const int qg = qrow;  // this lane's q row (softmax domain)
    const int ntile = t + 1;

    f16x8 aq[2];
#pragma unroll
    for (int ks = 0; ks < 2; ks++)
      aq[ks] = *(const f16x8*)(qbase + (size_t)qrow * kHL + ks * 32 + quad * 8);

    f32x4 acc[4];
    for (int nt = 0; nt < 4; nt++) acc[nt] = (f32x4){0.f, 0.f, 0.f, 0.f};
    float m_s = -3.0e38f;   // running row max, scaled-log2 domain (row l16)
    float l_part = 0.f;     // per-lane partial row sum (this lane's kv subset)

    // prologue: stage tile 0 into buffer 0
    __syncthreads();  // previous 'which' readers done before overwriting LDS
    {
      const int rl = w * 16;
      load_lds16(kbase + (size_t)(rl + rowA) * kHL + colSw, &sK[0][rl * 64]);
      load_lds16(vbase + (size_t)(rl + rowA) * kS + colSw, &sV[0][rl * 64]);
      load_lds16(kbase + (size_t)(rl + 8 + rowA) * kHL + colSw, &sK[0][(rl + 8) * 64]);
      load_lds16(vbase + (size_t)(rl + 8 + rowA) * kS + colSw, &sV[0][(rl + 8) * 64]);
    }
    int cur = 0;

    for (int it = 0; it < ntile; ++it) {
      const int kv0 = it * 64;
      __syncthreads();  // staging of buf[cur] drained (vmcnt before barrier)

      if (it + 1 < ntile) {  // prefetch next tile into the other buffer
        const int nkv = kv0 + 64;
        f16* dK = &sK[cur ^ 1][0];
        f16* dV = &sV[cur ^ 1][0];
        const int rl = w * 16;
        load_lds16(kbase + (size_t)(nkv + rl + rowA) * kHL + colSw, dK + rl * 64);
        load_lds16(vbase + (size_t)(rl + rowA) * kS + nkv + colSw, dV + rl * 64);
        load_lds16(kbase + (size_t)(nkv + rl + 8 + rowA) * kHL + colSw, dK + (rl + 8) * 64);
        load_lds16(vbase + (size_t)(rl + 8 + rowA) * kS + nkv + colSw, dV + (rl + 8) * 64);
      }
      const f16* sKc = &sK[cur][0];
      const f16* sVc = &sV[cur][0];

      // QK^T (swapped operands): lane holds q-row l16, kv = nt*16 + quad*4 + r
      f32x4 sc[4];
      for (int nt = 0; nt < 4; nt++) sc[nt] = (f32x4){0.f, 0.f, 0.f, 0.f};
#pragma unroll
      for (int ks = 0; ks < 2; ks++) {
        const int sw = ks ? sw1 : sw0;
        f16x8 bk[4];
#pragma unroll
        for (int nt = 0; nt < 4; nt++)
          bk[nt] = *(const f16x8*)&sKc[(nt * 16 + l16) * 64 + sw];
        __builtin_amdgcn_s_setprio(1);
#pragma unroll
        for (int nt = 0; nt < 4; nt++) sc[nt] = mfma16(bk[nt], aq[ks], sc[nt]);
        __builtin_amdgcn_s_setprio(0);
      }

      if (kv0 == q0) {  // diagonal tile: causal mask (raw domain)
#pragma unroll
        for (int nt = 0; nt < 4; nt++) {
#pragma unroll
          for (int r = 0; r < 4; r++) {
            int kvg = kv0 + nt * 16 + quad * 4 + r;
            if (kvg > qg) sc[nt][r] = -1.0e30f;
          }
        }
      }

      // in-lane row max + 2-step cross-quad reduce
      float tm = -3.0e38f;
#pragma unroll
      for (int nt = 0; nt < 4; nt++)
        tm = fmaxf(tm, fmaxf(fmaxf(sc[nt][0], sc[nt][1]), fmaxf(sc[nt][2], sc[nt][3])));
      tm = fmaxf(tm, __shfl_xor(tm, 16));
      tm = fmaxf(tm, __shfl_xor(tm, 32));
      const float tms = tm * cscale;

      if (!__all(tms <= m_s)) {  // some row's max grew: rescale (rare after warmup)
        const float mnew = fmaxf(m_s, tms);
        const float alpha = __builtin_amdgcn_exp2f(m_s - mnew);
        m_s = mnew;
        l_part *= alpha;
        float ar[4];
#pragma unroll
        for (int r = 0; r < 4; r++) ar[r] = __shfl(alpha, quad * 4 + r);
#pragma unroll
        for (int nt = 0; nt < 4; nt++)
#pragma unroll
          for (int r = 0; r < 4; r++) acc[nt][r] *= ar[r];
      }

      // p = exp2(sc*cscale - m); pack 4 kv-contiguous values per nt, one b64 write
      float ps = 0.f;
#pragma unroll
      for (int nt = 0; nt < 4; nt++) {
        f16x4 pk;
#pragma unroll
        for (int r = 0; r < 4; r++) {
          float p = __builtin_amdgcn_exp2f(__builtin_fmaf(sc[nt][r], cscale, -m_s));
          ps += p;
          pk[r] = (f16)p;
        }
        *(f16x4*)&sP[w][l16 * 72 + nt * 16 + quad * 4] = pk;
      }
      l_part += ps;

      // PV: A = P (rows = q), B = V (rows = vl) -> acc rows = q (quad*4+r), cols = vl
#pragma unroll
      for (int ks = 0; ks < 2; ks++) {
        const int sw = ks ? sw1 : sw0;
        f16x8 ap = *(const f16x8*)&sP[w][l16 * 72 + ks * 32 + quad * 8];
        f16x8 bv[4];
#pragma unroll
        for (int nt = 0; nt < 4; nt++)
          bv[nt] = *(const f16x8*)&sVc[(nt * 16 + l16) * 64 + sw];
        __builtin_amdgcn_s_setprio(1);
#pragma unroll
        for (int nt = 0; nt < 4; nt++) acc[nt] = mfma16(ap, bv[nt], acc[nt]);
        __builtin_amdgcn_s_setprio(0);
      }
      cur ^= 1;
    }

    // epilogue: finish deferred l reduction, broadcast to acc rows, normalize
    float lfull = l_part;
    lfull += __shfl_xor(lfull, 16);
    lfull += __shfl_xor(lfull, 32);
    float inv[4];
#pragma unroll
    for (int r = 0; r < 4; r++) inv[r] = 1.f / __shfl(lfull, quad * 4 + r);
#pragma unroll
    for (int r = 0; r < 4; r++) {
      int qout = q0 + w * 16 + quad * 4 + r;
      size_t base = (size_t)(b * kS + qout) * kHL + h * kL;
#pragma unroll
      for (int nt = 0; nt < 4; nt++)
        Ctx[base + nt * 16 + l16] = (f16)(acc[nt][r] * inv[r]);
    }
  }
}

extern "C" void kernel_launch(void* const* d_in, const int* in_sizes, int n_in,
                              void* d_out, int out_size, void* d_ws, size_t ws_size,
                              hipStream_t stream) {
  (void)in_sizes; (void)n_in; (void)out_size; (void)ws_size;
  const float* queries = (const float*)d_in[0];
  const float* keys    = (const float*)d_in[1];
  const float* values  = (const float*)d_in[2];
  const float* Wq      = (const float*)d_in[3];
  const float* bq      = (const float*)d_in[4];
  const float* Wlk     = (const float*)d_in[5];
  const float* blk     = (const float*)d_in[6];
  const float* Wlv     = (const float*)d_in[7];
  const float* blv     = (const float*)d_in[8];
  const float* Wkr     = (const float*)d_in[9];
  const float* Wvr     = (const float*)d_in[10];
  const float* Wout    = (const float*)d_in[11];
  const float* bout    = (const float*)d_in[12];

  char* ws = (char*)d_ws;
  size_t off = 0;
  auto alloc = [&](size_t bytes) {
    void* p = ws + off;
    off += (bytes + 255) & ~(size_t)255;
    return p;
  };
  f16* qb    = (f16*)alloc((size_t)kBS * kD * 2);
  f16* kb    = (f16*)alloc((size_t)kBS * kD * 2);
  f16* vb    = (f16*)alloc((size_t)kBS * kD * 2);
  f16* Wqlt  = (f16*)alloc((size_t)kHL * kD * 2);
  f16* Wlkt  = (f16*)alloc((size_t)kHL * kD * 2);
  f16* Wlvt  = (f16*)alloc((size_t)kHL * kD * 2);
  f16* W2t   = (f16*)alloc((size_t)kD * kHL * 2);
  float* bql = (float*)alloc(kHL * 4);
  f16* Qlat  = (f16*)alloc((size_t)kBS * kHL * 2);
  f16* LKb   = (f16*)alloc((size_t)kBS * kHL * 2);
  f16* LVb   = (f16*)alloc((size_t)kBS * kHL * 2);
  // prep-only buffers alias post-fold intermediates (dead by the time those are written):
  f16* Wq16  = Qlat;   // 8 MB (kD*kD f16), consumed by fold2 before gemm3 writes Qlat
  f16* WoutT = LKb;    // 8 MB, consumed by fold2 before gemm3 writes LKb
  // input-cast buffers alias post-attn intermediates:
  f16* LVtb = qb;  // LV transposed [b,h][l][s] — qb dead after gemm3
  f16* Ctx  = kb;  // attention output — kb dead after gemm3

  const int n4 = kBS * kD / 4;  // 2M float4 per q/k/v tensor
  cast4<<<dim3(n4 / 256, 1, 4), 256, 0, stream>>>(queries, keys, values, Wq, qb, kb, vb, Wq16);
  transpose3<<<dim3(32, 32, 3), 256, 0, stream>>>(Wlk, Wlv, Wout, Wlkt, Wlvt, WoutT);
  fold_bq<<<kHL / 256, 256, 0, stream>>>(bq, Wkr, bql);
  fold2<<<dim3(16, 16, 2), 256, 0, stream>>>(Wkr, Wvr, Wq16, WoutT, Wqlt, W2t);

  gemm3_f16<<<dim3(kHL / 128, kBS / 128, 3), 256, 0, stream>>>(
      qb, kb, vb, Wqlt, Wlkt, Wlvt, bql, blk, blv, Qlat, LKb, LVb, kHL, kD);

  transpose_lv<<<dim3(kS / 64, kB * kH), 256, 0, stream>>>(LVb, LVtb);
  attn<<<dim3(16, kB * kH), 256, 0, stream>>>(Qlat, LKb, LVtb, Ctx);
  gemm_f32<<<dim3(kD / 128, kBS / 128), 256, 0, stream>>>(Ctx, W2t, bout, (float*)d_out, kD, kHL);
}